// Round 6
// baseline (168.629 us; speedup 1.0000x reference)
//
#include <hip/hip_runtime.h>
#include <hip/hip_bf16.h>

#define B_   8192
#define F_   256
#define NFC  16            // feature chunks (blocks along F)
#define NF   (F_/NFC)      // 16 features per block
#define RPB  64            // rows per block
#define NSUB 2             // 2 subtiles of 16 rows per wave (2 waves)

typedef __attribute__((ext_vector_type(8))) short v8s;   // bf16x8 A/B frag (4 VGPR)
typedef __attribute__((ext_vector_type(4))) float v4f;   // f32x4 C/D frag
typedef __attribute__((ext_vector_type(4))) unsigned int v4u;

static __device__ __forceinline__ unsigned short f2bf(float f) {
    __hip_bfloat16 h = __float2bfloat16(f);
    return __builtin_bit_cast(unsigned short, h);
}

// single-instruction packed f32->bf16x2 (low=a, high=b), RNE (gfx950)
static __device__ __forceinline__ unsigned cvtpk(float a, float b) {
    unsigned r;
    asm("v_cvt_pk_bf16_f32 %0, %1, %2" : "=v"(r) : "v"(a), "v"(b));
    return r;
}

// ---------------- prep: pack W2/W3 into MFMA fragment order, bf16 ----------------
// Frags 0..3: W2 tile n as A-fragment for h2^T = W2^T @ h1^T:
//   lane(c,g) elem j  ->  W2[k = g*8+j][unit = n*16+c]
// Frags 4+kk*2+n2: W3 as B-fragment for t = h2 @ W3, u-map matching GEMM1's D order:
//   lane(c,g) elem j  ->  W3[u = (kk*2+(j>>2))*16 + g*4 + (j&3)][n2*16+c]
__global__ __launch_bounds__(256)
void honam_prep(const float* __restrict__ w2g, const float* __restrict__ w3g,
                unsigned short* __restrict__ wf)
{
    const int f   = blockIdx.x;
    const int tid = threadIdx.x;
    const float* w2 = w2g + (size_t)f * 2048;
    const float* w3 = w3g + (size_t)f * 2048;
    unsigned short* dst = wf + (size_t)f * 4096;
    for (int i = tid; i < 4096; i += 256) {
        const int frag = i >> 9;
        const int l    = (i >> 3) & 63;
        const int j    = i & 7;
        const int c    = l & 15;
        const int g    = l >> 4;
        float v;
        if (frag < 4) {
            v = w2[(g * 8 + j) * 64 + frag * 16 + c];            // W2[k][n*16+c]
        } else {
            const int kk = (frag - 4) >> 1;
            const int n2 = (frag - 4) & 1;
            const int u  = (kk * 2 + (j >> 2)) * 16 + g * 4 + (j & 3);
            v = w3[u * 32 + n2 * 16 + c];                        // W3[u][n2*16+c]
        }
        dst[i] = f2bf(v);
    }
}

// ---------------- Kernel 1: MFMA feature nets + p1/p2 ----------------
// 128-thread blocks (2 waves) for higher blocks/CU -> latency hiding.
__global__ __launch_bounds__(128, 4)
void honam_k1(const float* __restrict__ xg,
              const float* __restrict__ w1g, const float* __restrict__ b1g,
              const float* __restrict__ b2g, const float* __restrict__ b3g,
              const unsigned short* __restrict__ wfg,
              float* __restrict__ p1ws, float* __restrict__ p2ws)
{
    __shared__ float xs[NF][RPB];     // x-tile transposed: 16 features x 64 rows = 4KB

    const int tid  = threadIdx.x;
    const int wave = tid >> 6;        // 0..1
    const int lane = tid & 63;
    const int c16  = lane & 15;
    const int g4   = lane >> 4;

    const int bx = blockIdx.x;
    const int rb = bx >> 4;           // 0..127
    const int fc = bx & 15;           // 0..15
    const int r0 = rb * RPB;
    const int f0 = fc * NF;

    // ---- stage x-tile once, stored transposed ----
    {
        const int row  = tid >> 1;    // 0..63
        const int half = tid & 1;     // 0..1
        const float4 va = *(const float4*)&xg[(size_t)(r0 + row) * F_ + f0 + half * 8];
        const float4 vb = *(const float4*)&xg[(size_t)(r0 + row) * F_ + f0 + half * 8 + 4];
        const int fb = half * 8;
        xs[fb + 0][row] = va.x; xs[fb + 1][row] = va.y;
        xs[fb + 2][row] = va.z; xs[fb + 3][row] = va.w;
        xs[fb + 4][row] = vb.x; xs[fb + 5][row] = vb.y;
        xs[fb + 6][row] = vb.z; xs[fb + 7][row] = vb.w;
    }
    __syncthreads();   // the only barrier in this kernel

    float pacc1[NSUB][2][4];
    float pacc2[NSUB][2][4];
#pragma unroll
    for (int s = 0; s < NSUB; ++s)
#pragma unroll
        for (int n2 = 0; n2 < 2; ++n2)
#pragma unroll
            for (int j = 0; j < 4; ++j) { pacc1[s][n2][j] = 0.f; pacc2[s][n2][j] = 0.f; }

    // per-lane weight-frag base: feature stride 8192 B, lane offset 16 B
    const char* wlane = (const char*)wfg + (size_t)f0 * 8192 + (size_t)lane * 16;

    v8s wcur[8], wnxt[8];
#pragma unroll
    for (int fr = 0; fr < 8; ++fr)
        wcur[fr] = *(const v8s*)(wlane + fr * 1024);

#pragma unroll 2
    for (int fi = 0; fi < NF; ++fi) {
        const int f = f0 + fi;
        // prefetch next feature's frags (one full compute phase of latency hiding)
        if (fi + 1 < NF) {
            const char* wn = wlane + (size_t)(fi + 1) * 8192;
#pragma unroll
            for (int fr = 0; fr < 8; ++fr)
                wnxt[fr] = *(const v8s*)(wn + fr * 1024);
        }
        // hoist LDS x reads for both subtiles
        float xm[NSUB];
#pragma unroll
        for (int s = 0; s < NSUB; ++s)
            xm[s] = xs[fi][s * 32 + wave * 16 + c16];

        // per-feature scalars (f32, L1-cached)
        const float4 w1a = *(const float4*)&w1g[f * 32 + g4 * 8];
        const float4 w1b = *(const float4*)&w1g[f * 32 + g4 * 8 + 4];
        const float4 b1a = *(const float4*)&b1g[f * 32 + g4 * 8];
        const float4 b1b = *(const float4*)&b1g[f * 32 + g4 * 8 + 4];
        const float w1v[8] = {w1a.x, w1a.y, w1a.z, w1a.w, w1b.x, w1b.y, w1b.z, w1b.w};
        const float b1v[8] = {b1a.x, b1a.y, b1a.z, b1a.w, b1b.x, b1b.y, b1b.z, b1b.w};
        // b2 as per-reg C-in for swapped GEMM1: reg j <-> unit n*16+g4*4+j
        float4 b2c[4];
#pragma unroll
        for (int n = 0; n < 4; ++n)
            b2c[n] = *(const float4*)&b2g[f * 64 + n * 16 + g4 * 4];
        float b3v[2];
#pragma unroll
        for (int n = 0; n < 2; ++n) b3v[n] = b3g[f * 32 + n * 16 + c16];

#pragma unroll
        for (int sub = 0; sub < NSUB; ++sub) {
            // h1 as B-frag of GEMM1: lane(c16,g4) elem j = h1[m=c16][k=g4*8+j]
            unsigned h1p[4];
#pragma unroll
            for (int jj = 0; jj < 4; ++jj) {
                const float e0 = fmaxf(fmaf(xm[sub], w1v[2 * jj],     b1v[2 * jj]),     0.f);
                const float e1 = fmaxf(fmaf(xm[sub], w1v[2 * jj + 1], b1v[2 * jj + 1]), 0.f);
                h1p[jj] = cvtpk(e0, e1);
            }
            const v8s bh1 = __builtin_bit_cast(v8s, (v4u){h1p[0], h1p[1], h1p[2], h1p[3]});

            // GEMM1 (swapped): h2^T = W2^T @ h1^T + b2 ; D reg j = h2[m=c16][n*16+g4*4+j]
            v4f acc2[4];
#pragma unroll
            for (int n = 0; n < 4; ++n)
                acc2[n] = __builtin_amdgcn_mfma_f32_16x16x32_bf16(
                    wcur[n], bh1, (v4f){b2c[n].x, b2c[n].y, b2c[n].z, b2c[n].w}, 0, 0, 0);

            // relu + pack: D-frags ARE GEMM2's A-frags under the prep-side u-map
            unsigned q[8];
#pragma unroll
            for (int n = 0; n < 4; ++n) {
                q[2 * n]     = cvtpk(fmaxf(acc2[n][0], 0.f), fmaxf(acc2[n][1], 0.f));
                q[2 * n + 1] = cvtpk(fmaxf(acc2[n][2], 0.f), fmaxf(acc2[n][3], 0.f));
            }
            const v8s a2k0 = __builtin_bit_cast(v8s, (v4u){q[0], q[1], q[2], q[3]});
            const v8s a2k1 = __builtin_bit_cast(v8s, (v4u){q[4], q[5], q[6], q[7]});

            // GEMM2: t = relu(h2 @ W3 + b3)
            v4f acc3[2];
#pragma unroll
            for (int n2 = 0; n2 < 2; ++n2) {
                acc3[n2] = __builtin_amdgcn_mfma_f32_16x16x32_bf16(
                    a2k0, wcur[4 + n2], (v4f){b3v[n2], b3v[n2], b3v[n2], b3v[n2]}, 0, 0, 0);
                acc3[n2] = __builtin_amdgcn_mfma_f32_16x16x32_bf16(
                    a2k1, wcur[6 + n2], acc3[n2], 0, 0, 0);
            }
#pragma unroll
            for (int n2 = 0; n2 < 2; ++n2)
#pragma unroll
                for (int j = 0; j < 4; ++j) {
                    const float t = fmaxf(acc3[n2][j], 0.f);
                    pacc1[sub][n2][j] += t;
                    pacc2[sub][n2][j] = fmaf(t, t, pacc2[sub][n2][j]);
                }
        }
        // rotate prefetch buffer (renamed away under unroll 2)
#pragma unroll
        for (int fr = 0; fr < 8; ++fr) wcur[fr] = wnxt[fr];
    }

    // accumulate partial power sums (NFC=16 contenders per address)
#pragma unroll
    for (int sub = 0; sub < NSUB; ++sub)
#pragma unroll
        for (int n2 = 0; n2 < 2; ++n2)
#pragma unroll
            for (int j = 0; j < 4; ++j) {
                const int row = r0 + sub * 32 + wave * 16 + g4 * 4 + j;
                const int col = n2 * 16 + c16;
                atomicAdd(&p1ws[row * 32 + col], pacc1[sub][n2][j]);
                atomicAdd(&p2ws[row * 32 + col], pacc2[sub][n2][j]);
            }
}

// ---------------- Kernel 2: Newton identities + output head ----------------
__global__ __launch_bounds__(256)
void honam_k2(const float* __restrict__ p1ws, const float* __restrict__ p2ws,
              const float* __restrict__ woutg, const float* __restrict__ boutg,
              float* __restrict__ outg)
{
    const int tid = threadIdx.x;
    const int o   = tid & 31;
    const int r   = blockIdx.x * 8 + (tid >> 5);
    const float v1 = p1ws[r * 32 + o];
    const float v2 = p2ws[r * 32 + o];
    const float wa = woutg[o];
    const float wb = woutg[32 + o];
    float val = v1 * wa + 0.5f * (v1 * v1 - v2) * wb;
#pragma unroll
    for (int off = 16; off > 0; off >>= 1)
        val += __shfl_down(val, off, 32);
    if (o == 0) outg[r] = val + boutg[0];
}

extern "C" void kernel_launch(void* const* d_in, const int* in_sizes, int n_in,
                              void* d_out, int out_size, void* d_ws, size_t ws_size,
                              hipStream_t stream)
{
    const float* xg    = (const float*)d_in[0];
    const float* w1g   = (const float*)d_in[1];
    const float* b1g   = (const float*)d_in[2];
    const float* w2g   = (const float*)d_in[3];
    const float* b2g   = (const float*)d_in[4];
    const float* w3g   = (const float*)d_in[5];
    const float* b3g   = (const float*)d_in[6];
    const float* woutg = (const float*)d_in[7];
    const float* boutg = (const float*)d_in[8];
    float* outg = (float*)d_out;

    float* p1ws = (float*)d_ws;                                     // 1 MB
    float* p2ws = p1ws + (size_t)B_ * 32;                           // 1 MB
    unsigned short* wf = (unsigned short*)(p2ws + (size_t)B_ * 32); // 2 MB packed weights

    hipMemsetAsync(d_ws, 0, (size_t)B_ * 32 * 2 * sizeof(float), stream);

    honam_prep<<<dim3(F_), dim3(256), 0, stream>>>(w2g, w3g, wf);

    honam_k1<<<dim3((B_ / RPB) * NFC), dim3(128), 0, stream>>>(
        xg, w1g, b1g, b2g, b3g, wf, p1ws, p2ws);

    honam_k2<<<dim3(B_ / 8), dim3(256), 0, stream>>>(p1ws, p2ws, woutg, boutg, outg);
}

// Round 7
// 85.836 us; speedup vs baseline: 1.9645x; 1.9645x over previous
//
#include <hip/hip_runtime.h>
#include <hip/hip_bf16.h>

#define B_   8192
#define F_   256
#define NFC  32            // feature chunks (blocks along F)
#define NF   (F_/NFC)      // 8 features per block
#define RPB  128           // rows per block
#define NSUB 2             // 2 subtiles of 64 rows (4 waves x 16 rows)

typedef __attribute__((ext_vector_type(8))) short v8s;   // bf16x8 A/B frag (4 VGPR)
typedef __attribute__((ext_vector_type(4))) float v4f;   // f32x4 C/D frag
typedef __attribute__((ext_vector_type(4))) unsigned int v4u;

static __device__ __forceinline__ unsigned short f2bf(float f) {
    __hip_bfloat16 h = __float2bfloat16(f);
    return __builtin_bit_cast(unsigned short, h);
}

// single-instruction packed f32->bf16x2 (low=a, high=b), RNE (gfx950)
static __device__ __forceinline__ unsigned cvtpk(float a, float b) {
    unsigned r;
    asm("v_cvt_pk_bf16_f32 %0, %1, %2" : "=v"(r) : "v"(a), "v"(b));
    return r;
}

// ---------------- prep: pack W2/W3 into MFMA fragment order, bf16 ----------------
// Frags 0..3: W2 tile n as A-fragment for h2^T = W2^T @ h1^T:
//   lane(c,g) elem j  ->  W2[k = g*8+j][unit = n*16+c]
// Frags 4+kk*2+n2: W3 as B-fragment for t = h2 @ W3, u-map matching GEMM1's D order:
//   lane(c,g) elem j  ->  W3[u = (kk*2+(j>>2))*16 + g*4 + (j&3)][n2*16+c]
__global__ __launch_bounds__(256)
void honam_prep(const float* __restrict__ w2g, const float* __restrict__ w3g,
                unsigned short* __restrict__ wf)
{
    const int f   = blockIdx.x;
    const int tid = threadIdx.x;
    const float* w2 = w2g + (size_t)f * 2048;
    const float* w3 = w3g + (size_t)f * 2048;
    unsigned short* dst = wf + (size_t)f * 4096;
    for (int i = tid; i < 4096; i += 256) {
        const int frag = i >> 9;
        const int l    = (i >> 3) & 63;
        const int j    = i & 7;
        const int c    = l & 15;
        const int g    = l >> 4;
        float v;
        if (frag < 4) {
            v = w2[(g * 8 + j) * 64 + frag * 16 + c];            // W2[k][n*16+c]
        } else {
            const int kk = (frag - 4) >> 1;
            const int n2 = (frag - 4) & 1;
            const int u  = (kk * 2 + (j >> 2)) * 16 + g * 4 + (j & 3);
            v = w3[u * 32 + n2 * 16 + c];                        // W3[u][n2*16+c]
        }
        dst[i] = f2bf(v);
    }
}

// ---------------- Kernel 1: MFMA feature nets + p1/p2 ----------------
// Round-5 schedule (VGPR 84, reg-prefetch one feature ahead), grid doubled along F.
__global__ __launch_bounds__(256, 3)
void honam_k1(const float* __restrict__ xg,
              const float* __restrict__ w1g, const float* __restrict__ b1g,
              const float* __restrict__ b2g, const float* __restrict__ b3g,
              const unsigned short* __restrict__ wfg,
              float* __restrict__ p1ws, float* __restrict__ p2ws)
{
    __shared__ float xs[NF][RPB];     // x-tile transposed: 8 features x 128 rows = 4KB

    const int tid  = threadIdx.x;
    const int wave = tid >> 6;
    const int lane = tid & 63;
    const int c16  = lane & 15;
    const int g4   = lane >> 4;

    const int bx = blockIdx.x;
    const int rb = bx >> 5;           // 0..63
    const int fc = bx & 31;           // 0..31
    const int r0 = rb * RPB;
    const int f0 = fc * NF;

    // ---- stage x-tile once, stored transposed ----
    {
        const int row  = tid >> 1;    // 0..127
        const int half = tid & 1;     // 0..1
        const float4 va = *(const float4*)&xg[(size_t)(r0 + row) * F_ + f0 + half * 4];
        const int fb = half * 4;
        xs[fb + 0][row] = va.x; xs[fb + 1][row] = va.y;
        xs[fb + 2][row] = va.z; xs[fb + 3][row] = va.w;
    }
    __syncthreads();   // the only barrier in this kernel

    float pacc1[NSUB][2][4];
    float pacc2[NSUB][2][4];
#pragma unroll
    for (int s = 0; s < NSUB; ++s)
#pragma unroll
        for (int n2 = 0; n2 < 2; ++n2)
#pragma unroll
            for (int j = 0; j < 4; ++j) { pacc1[s][n2][j] = 0.f; pacc2[s][n2][j] = 0.f; }

    // per-lane weight-frag base: feature stride 8192 B, lane offset 16 B
    const char* wlane = (const char*)wfg + (size_t)f0 * 8192 + (size_t)lane * 16;

    v8s wcur[8], wnxt[8];
#pragma unroll
    for (int fr = 0; fr < 8; ++fr)
        wcur[fr] = *(const v8s*)(wlane + fr * 1024);

#pragma unroll 2
    for (int fi = 0; fi < NF; ++fi) {
        const int f = f0 + fi;
        // prefetch next feature's frags (one full compute phase of latency hiding)
        if (fi + 1 < NF) {
            const char* wn = wlane + (size_t)(fi + 1) * 8192;
#pragma unroll
            for (int fr = 0; fr < 8; ++fr)
                wnxt[fr] = *(const v8s*)(wn + fr * 1024);
        }
        // hoist LDS x reads for both subtiles
        float xm[NSUB];
#pragma unroll
        for (int s = 0; s < NSUB; ++s)
            xm[s] = xs[fi][s * 64 + wave * 16 + c16];

        // per-feature scalars (f32, L1-cached)
        const float4 w1a = *(const float4*)&w1g[f * 32 + g4 * 8];
        const float4 w1b = *(const float4*)&w1g[f * 32 + g4 * 8 + 4];
        const float4 b1a = *(const float4*)&b1g[f * 32 + g4 * 8];
        const float4 b1b = *(const float4*)&b1g[f * 32 + g4 * 8 + 4];
        const float w1v[8] = {w1a.x, w1a.y, w1a.z, w1a.w, w1b.x, w1b.y, w1b.z, w1b.w};
        const float b1v[8] = {b1a.x, b1a.y, b1a.z, b1a.w, b1b.x, b1b.y, b1b.z, b1b.w};
        // b2 as per-reg C-in for swapped GEMM1: reg j <-> unit n*16+g4*4+j
        float4 b2c[4];
#pragma unroll
        for (int n = 0; n < 4; ++n)
            b2c[n] = *(const float4*)&b2g[f * 64 + n * 16 + g4 * 4];
        float b3v[2];
#pragma unroll
        for (int n = 0; n < 2; ++n) b3v[n] = b3g[f * 32 + n * 16 + c16];

#pragma unroll
        for (int sub = 0; sub < NSUB; ++sub) {
            // h1 as B-frag of GEMM1: lane(c16,g4) elem j = h1[m=c16][k=g4*8+j]
            unsigned h1p[4];
#pragma unroll
            for (int jj = 0; jj < 4; ++jj) {
                const float e0 = fmaxf(fmaf(xm[sub], w1v[2 * jj],     b1v[2 * jj]),     0.f);
                const float e1 = fmaxf(fmaf(xm[sub], w1v[2 * jj + 1], b1v[2 * jj + 1]), 0.f);
                h1p[jj] = cvtpk(e0, e1);
            }
            const v8s bh1 = __builtin_bit_cast(v8s, (v4u){h1p[0], h1p[1], h1p[2], h1p[3]});

            // GEMM1 (swapped): h2^T = W2^T @ h1^T + b2 ; D reg j = h2[m=c16][n*16+g4*4+j]
            v4f acc2[4];
#pragma unroll
            for (int n = 0; n < 4; ++n)
                acc2[n] = __builtin_amdgcn_mfma_f32_16x16x32_bf16(
                    wcur[n], bh1, (v4f){b2c[n].x, b2c[n].y, b2c[n].z, b2c[n].w}, 0, 0, 0);

            // relu + pack: D-frags ARE GEMM2's A-frags under the prep-side u-map
            unsigned q[8];
#pragma unroll
            for (int n = 0; n < 4; ++n) {
                q[2 * n]     = cvtpk(fmaxf(acc2[n][0], 0.f), fmaxf(acc2[n][1], 0.f));
                q[2 * n + 1] = cvtpk(fmaxf(acc2[n][2], 0.f), fmaxf(acc2[n][3], 0.f));
            }
            const v8s a2k0 = __builtin_bit_cast(v8s, (v4u){q[0], q[1], q[2], q[3]});
            const v8s a2k1 = __builtin_bit_cast(v8s, (v4u){q[4], q[5], q[6], q[7]});

            // GEMM2: t = relu(h2 @ W3 + b3)
            v4f acc3[2];
#pragma unroll
            for (int n2 = 0; n2 < 2; ++n2) {
                acc3[n2] = __builtin_amdgcn_mfma_f32_16x16x32_bf16(
                    a2k0, wcur[4 + n2], (v4f){b3v[n2], b3v[n2], b3v[n2], b3v[n2]}, 0, 0, 0);
                acc3[n2] = __builtin_amdgcn_mfma_f32_16x16x32_bf16(
                    a2k1, wcur[6 + n2], acc3[n2], 0, 0, 0);
            }
#pragma unroll
            for (int n2 = 0; n2 < 2; ++n2)
#pragma unroll
                for (int j = 0; j < 4; ++j) {
                    const float t = fmaxf(acc3[n2][j], 0.f);
                    pacc1[sub][n2][j] += t;
                    pacc2[sub][n2][j] = fmaf(t, t, pacc2[sub][n2][j]);
                }
        }
        // rotate prefetch buffer (renamed away under unroll 2)
#pragma unroll
        for (int fr = 0; fr < 8; ++fr) wcur[fr] = wnxt[fr];
    }

    // accumulate partial power sums (NFC=32 contenders per address)
#pragma unroll
    for (int sub = 0; sub < NSUB; ++sub)
#pragma unroll
        for (int n2 = 0; n2 < 2; ++n2)
#pragma unroll
            for (int j = 0; j < 4; ++j) {
                const int row = r0 + sub * 64 + wave * 16 + g4 * 4 + j;
                const int col = n2 * 16 + c16;
                atomicAdd(&p1ws[row * 32 + col], pacc1[sub][n2][j]);
                atomicAdd(&p2ws[row * 32 + col], pacc2[sub][n2][j]);
            }
}

// ---------------- Kernel 2: Newton identities + output head ----------------
__global__ __launch_bounds__(256)
void honam_k2(const float* __restrict__ p1ws, const float* __restrict__ p2ws,
              const float* __restrict__ woutg, const float* __restrict__ boutg,
              float* __restrict__ outg)
{
    const int tid = threadIdx.x;
    const int o   = tid & 31;
    const int r   = blockIdx.x * 8 + (tid >> 5);
    const float v1 = p1ws[r * 32 + o];
    const float v2 = p2ws[r * 32 + o];
    const float wa = woutg[o];
    const float wb = woutg[32 + o];
    float val = v1 * wa + 0.5f * (v1 * v1 - v2) * wb;
#pragma unroll
    for (int off = 16; off > 0; off >>= 1)
        val += __shfl_down(val, off, 32);
    if (o == 0) outg[r] = val + boutg[0];
}

extern "C" void kernel_launch(void* const* d_in, const int* in_sizes, int n_in,
                              void* d_out, int out_size, void* d_ws, size_t ws_size,
                              hipStream_t stream)
{
    const float* xg    = (const float*)d_in[0];
    const float* w1g   = (const float*)d_in[1];
    const float* b1g   = (const float*)d_in[2];
    const float* w2g   = (const float*)d_in[3];
    const float* b2g   = (const float*)d_in[4];
    const float* w3g   = (const float*)d_in[5];
    const float* b3g   = (const float*)d_in[6];
    const float* woutg = (const float*)d_in[7];
    const float* boutg = (const float*)d_in[8];
    float* outg = (float*)d_out;

    float* p1ws = (float*)d_ws;                                     // 1 MB
    float* p2ws = p1ws + (size_t)B_ * 32;                           // 1 MB
    unsigned short* wf = (unsigned short*)(p2ws + (size_t)B_ * 32); // 2 MB packed weights

    hipMemsetAsync(d_ws, 0, (size_t)B_ * 32 * 2 * sizeof(float), stream);

    honam_prep<<<dim3(F_), dim3(256), 0, stream>>>(w2g, w3g, wf);

    honam_k1<<<dim3((B_ / RPB) * NFC), dim3(256), 0, stream>>>(
        xg, w1g, b1g, b2g, b3g, wf, p1ws, p2ws);

    honam_k2<<<dim3(B_ / 8), dim3(256), 0, stream>>>(p1ws, p2ws, woutg, boutg, outg);
}

// Round 8
// 81.100 us; speedup vs baseline: 2.0793x; 1.0584x over previous
//
#include <hip/hip_runtime.h>
#include <hip/hip_bf16.h>

#define B_   8192
#define F_   256
#define NFC  16            // feature chunks (blocks along F)
#define NF   (F_/NFC)      // 16 features per block
#define RPB  256           // rows per block
#define NSUB 4             // 4 subtiles of 64 rows (4 waves x 16 rows) -> ILP 4

typedef __attribute__((ext_vector_type(8))) short v8s;   // bf16x8 A/B frag (4 VGPR)
typedef __attribute__((ext_vector_type(4))) float v4f;   // f32x4 C/D frag
typedef __attribute__((ext_vector_type(4))) unsigned int v4u;

static __device__ __forceinline__ unsigned short f2bf(float f) {
    __hip_bfloat16 h = __float2bfloat16(f);
    return __builtin_bit_cast(unsigned short, h);
}

// single-instruction packed f32->bf16x2 (low=a, high=b), RNE (gfx950)
static __device__ __forceinline__ unsigned cvtpk(float a, float b) {
    unsigned r;
    asm("v_cvt_pk_bf16_f32 %0, %1, %2" : "=v"(r) : "v"(a), "v"(b));
    return r;
}

// ---------------- prep: pack W2/W3 into MFMA fragment order, bf16 ----------------
// Frags 0..3: W2 tile n as A-fragment for h2^T = W2^T @ h1^T:
//   lane(c,g) elem j  ->  W2[k = g*8+j][unit = n*16+c]
// Frags 4+kk*2+n2: W3 as B-fragment for t = h2 @ W3, u-map matching GEMM1's D order:
//   lane(c,g) elem j  ->  W3[u = (kk*2+(j>>2))*16 + g*4 + (j&3)][n2*16+c]
__global__ __launch_bounds__(256)
void honam_prep(const float* __restrict__ w2g, const float* __restrict__ w3g,
                unsigned short* __restrict__ wf)
{
    const int f   = blockIdx.x;
    const int tid = threadIdx.x;
    const float* w2 = w2g + (size_t)f * 2048;
    const float* w3 = w3g + (size_t)f * 2048;
    unsigned short* dst = wf + (size_t)f * 4096;
    for (int i = tid; i < 4096; i += 256) {
        const int frag = i >> 9;
        const int l    = (i >> 3) & 63;
        const int j    = i & 7;
        const int c    = l & 15;
        const int g    = l >> 4;
        float v;
        if (frag < 4) {
            v = w2[(g * 8 + j) * 64 + frag * 16 + c];            // W2[k][n*16+c]
        } else {
            const int kk = (frag - 4) >> 1;
            const int n2 = (frag - 4) & 1;
            const int u  = (kk * 2 + (j >> 2)) * 16 + g * 4 + (j & 3);
            v = w3[u * 32 + n2 * 16 + c];                        // W3[u][n2*16+c]
        }
        dst[i] = f2bf(v);
    }
}

// ---------------- Kernel 1: MFMA feature nets + p1/p2, ILP-4 chains per wave ----------------
__global__ __launch_bounds__(256, 2)
void honam_k1(const float* __restrict__ xg,
              const float* __restrict__ w1g, const float* __restrict__ b1g,
              const float* __restrict__ b2g, const float* __restrict__ b3g,
              const unsigned short* __restrict__ wfg,
              float* __restrict__ p1ws, float* __restrict__ p2ws)
{
    __shared__ float xs[NF][RPB + 4];   // x-tile transposed, padded stride (16.6 KB)

    const int tid  = threadIdx.x;
    const int wave = tid >> 6;
    const int lane = tid & 63;
    const int c16  = lane & 15;
    const int g4   = lane >> 4;

    const int bx = blockIdx.x;
    const int rb = bx >> 4;           // 0..31
    const int fc = bx & 15;           // 0..15
    const int r0 = rb * RPB;
    const int f0 = fc * NF;

    // ---- stage x-tile once: 4 lanes per row, 4 passes of 64 rows ----
    {
        const int q   = tid & 3;      // which float4 of the row (features q*4..q*4+3)
        const int rr  = tid >> 2;     // 0..63
#pragma unroll
        for (int p = 0; p < 4; ++p) {
            const int row = p * 64 + rr;
            const float4 v = *(const float4*)&xg[(size_t)(r0 + row) * F_ + f0 + q * 4];
            xs[q * 4 + 0][row] = v.x; xs[q * 4 + 1][row] = v.y;
            xs[q * 4 + 2][row] = v.z; xs[q * 4 + 3][row] = v.w;
        }
    }
    __syncthreads();   // the only barrier in this kernel

    float pacc1[NSUB][2][4];
    float pacc2[NSUB][2][4];
#pragma unroll
    for (int s = 0; s < NSUB; ++s)
#pragma unroll
        for (int n2 = 0; n2 < 2; ++n2)
#pragma unroll
            for (int j = 0; j < 4; ++j) { pacc1[s][n2][j] = 0.f; pacc2[s][n2][j] = 0.f; }

    // per-lane weight-frag base: feature stride 8192 B, lane offset 16 B
    const char* wlane = (const char*)wfg + (size_t)f0 * 8192 + (size_t)lane * 16;

#pragma unroll 2
    for (int fi = 0; fi < NF; ++fi) {
        const int f = f0 + fi;
        // weight frags from global (2 MB hot set, L2-resident, coalesced 16B/lane)
        const char* wp = wlane + (size_t)fi * 8192;
        v8s wfr[8];
#pragma unroll
        for (int fr = 0; fr < 8; ++fr)
            wfr[fr] = *(const v8s*)(wp + fr * 1024);

        // hoist LDS x reads for all 4 subtiles
        float xm[NSUB];
#pragma unroll
        for (int s = 0; s < NSUB; ++s)
            xm[s] = xs[fi][s * 64 + wave * 16 + c16];

        // per-feature scalars (f32, L1-cached)
        const float4 w1a = *(const float4*)&w1g[f * 32 + g4 * 8];
        const float4 w1b = *(const float4*)&w1g[f * 32 + g4 * 8 + 4];
        const float4 b1a = *(const float4*)&b1g[f * 32 + g4 * 8];
        const float4 b1b = *(const float4*)&b1g[f * 32 + g4 * 8 + 4];
        const float w1v[8] = {w1a.x, w1a.y, w1a.z, w1a.w, w1b.x, w1b.y, w1b.z, w1b.w};
        const float b1v[8] = {b1a.x, b1a.y, b1a.z, b1a.w, b1b.x, b1b.y, b1b.z, b1b.w};
        // b2 as per-reg C-in for swapped GEMM1: reg j <-> unit n*16+g4*4+j
        float4 b2c[4];
#pragma unroll
        for (int n = 0; n < 4; ++n)
            b2c[n] = *(const float4*)&b2g[f * 64 + n * 16 + g4 * 4];
        float b3v[2];
#pragma unroll
        for (int n = 0; n < 2; ++n) b3v[n] = b3g[f * 32 + n * 16 + c16];

        // 4 independent 16-row chains (ILP 4)
#pragma unroll
        for (int sub = 0; sub < NSUB; ++sub) {
            // h1 as B-frag of GEMM1: lane(c16,g4) elem j = h1[m=c16][k=g4*8+j]
            unsigned h1p[4];
#pragma unroll
            for (int jj = 0; jj < 4; ++jj) {
                const float e0 = fmaxf(fmaf(xm[sub], w1v[2 * jj],     b1v[2 * jj]),     0.f);
                const float e1 = fmaxf(fmaf(xm[sub], w1v[2 * jj + 1], b1v[2 * jj + 1]), 0.f);
                h1p[jj] = cvtpk(e0, e1);
            }
            const v8s bh1 = __builtin_bit_cast(v8s, (v4u){h1p[0], h1p[1], h1p[2], h1p[3]});

            // GEMM1 (swapped): h2^T = W2^T @ h1^T + b2 ; D reg j = h2[m=c16][n*16+g4*4+j]
            v4f acc2[4];
#pragma unroll
            for (int n = 0; n < 4; ++n)
                acc2[n] = __builtin_amdgcn_mfma_f32_16x16x32_bf16(
                    wfr[n], bh1, (v4f){b2c[n].x, b2c[n].y, b2c[n].z, b2c[n].w}, 0, 0, 0);

            // relu + pack: D-frags ARE GEMM2's A-frags under the prep-side u-map
            unsigned q[8];
#pragma unroll
            for (int n = 0; n < 4; ++n) {
                q[2 * n]     = cvtpk(fmaxf(acc2[n][0], 0.f), fmaxf(acc2[n][1], 0.f));
                q[2 * n + 1] = cvtpk(fmaxf(acc2[n][2], 0.f), fmaxf(acc2[n][3], 0.f));
            }
            const v8s a2k0 = __builtin_bit_cast(v8s, (v4u){q[0], q[1], q[2], q[3]});
            const v8s a2k1 = __builtin_bit_cast(v8s, (v4u){q[4], q[5], q[6], q[7]});

            // GEMM2: t = relu(h2 @ W3 + b3)
            v4f acc3[2];
#pragma unroll
            for (int n2 = 0; n2 < 2; ++n2) {
                acc3[n2] = __builtin_amdgcn_mfma_f32_16x16x32_bf16(
                    a2k0, wfr[4 + n2], (v4f){b3v[n2], b3v[n2], b3v[n2], b3v[n2]}, 0, 0, 0);
                acc3[n2] = __builtin_amdgcn_mfma_f32_16x16x32_bf16(
                    a2k1, wfr[6 + n2], acc3[n2], 0, 0, 0);
            }
#pragma unroll
            for (int n2 = 0; n2 < 2; ++n2)
#pragma unroll
                for (int j = 0; j < 4; ++j) {
                    const float t = fmaxf(acc3[n2][j], 0.f);
                    pacc1[sub][n2][j] += t;
                    pacc2[sub][n2][j] = fmaf(t, t, pacc2[sub][n2][j]);
                }
        }
    }

    // accumulate partial power sums (NFC=16 contenders per address)
#pragma unroll
    for (int sub = 0; sub < NSUB; ++sub)
#pragma unroll
        for (int n2 = 0; n2 < 2; ++n2)
#pragma unroll
            for (int j = 0; j < 4; ++j) {
                const int row = r0 + sub * 64 + wave * 16 + g4 * 4 + j;
                const int col = n2 * 16 + c16;
                atomicAdd(&p1ws[row * 32 + col], pacc1[sub][n2][j]);
                atomicAdd(&p2ws[row * 32 + col], pacc2[sub][n2][j]);
            }
}

// ---------------- Kernel 2: Newton identities + output head ----------------
__global__ __launch_bounds__(256)
void honam_k2(const float* __restrict__ p1ws, const float* __restrict__ p2ws,
              const float* __restrict__ woutg, const float* __restrict__ boutg,
              float* __restrict__ outg)
{
    const int tid = threadIdx.x;
    const int o   = tid & 31;
    const int r   = blockIdx.x * 8 + (tid >> 5);
    const float v1 = p1ws[r * 32 + o];
    const float v2 = p2ws[r * 32 + o];
    const float wa = woutg[o];
    const float wb = woutg[32 + o];
    float val = v1 * wa + 0.5f * (v1 * v1 - v2) * wb;
#pragma unroll
    for (int off = 16; off > 0; off >>= 1)
        val += __shfl_down(val, off, 32);
    if (o == 0) outg[r] = val + boutg[0];
}

extern "C" void kernel_launch(void* const* d_in, const int* in_sizes, int n_in,
                              void* d_out, int out_size, void* d_ws, size_t ws_size,
                              hipStream_t stream)
{
    const float* xg    = (const float*)d_in[0];
    const float* w1g   = (const float*)d_in[1];
    const float* b1g   = (const float*)d_in[2];
    const float* w2g   = (const float*)d_in[3];
    const float* b2g   = (const float*)d_in[4];
    const float* w3g   = (const float*)d_in[5];
    const float* b3g   = (const float*)d_in[6];
    const float* woutg = (const float*)d_in[7];
    const float* boutg = (const float*)d_in[8];
    float* outg = (float*)d_out;

    float* p1ws = (float*)d_ws;                                     // 1 MB
    float* p2ws = p1ws + (size_t)B_ * 32;                           // 1 MB
    unsigned short* wf = (unsigned short*)(p2ws + (size_t)B_ * 32); // 2 MB packed weights

    hipMemsetAsync(d_ws, 0, (size_t)B_ * 32 * 2 * sizeof(float), stream);

    honam_prep<<<dim3(F_), dim3(256), 0, stream>>>(w2g, w3g, wf);

    honam_k1<<<dim3((B_ / RPB) * NFC), dim3(256), 0, stream>>>(
        xg, w1g, b1g, b2g, b3g, wf, p1ws, p2ws);

    honam_k2<<<dim3(B_ / 8), dim3(256), 0, stream>>>(p1ws, p2ws, woutg, boutg, outg);
}

// Round 9
// 63.775 us; speedup vs baseline: 2.6441x; 1.2717x over previous
//
#include <hip/hip_runtime.h>
#include <hip/hip_bf16.h>

#define B_   8192
#define F_   256
#define NFC  16            // feature chunks (blocks along F)
#define NF   (F_/NFC)      // 16 features per block
#define RPB  128           // rows per block
#define NSUB 2             // 2 subtiles of 64 rows (4 waves x 16 rows)

typedef __attribute__((ext_vector_type(8))) short v8s;   // bf16x8 A/B frag (4 VGPR)
typedef __attribute__((ext_vector_type(4))) float v4f;   // f32x4 C/D frag
typedef __attribute__((ext_vector_type(4))) unsigned int v4u;

static __device__ __forceinline__ unsigned short f2bf(float f) {
    __hip_bfloat16 h = __float2bfloat16(f);
    return __builtin_bit_cast(unsigned short, h);
}

// single-instruction packed f32->bf16x2 (low=a, high=b), RNE (gfx950)
static __device__ __forceinline__ unsigned cvtpk(float a, float b) {
    unsigned r;
    asm("v_cvt_pk_bf16_f32 %0, %1, %2" : "=v"(r) : "v"(a), "v"(b));
    return r;
}

// ---------------- prep: pack W2/W3 into MFMA fragment order, bf16 ----------------
// Frags 0..3: W2 tile n as A-fragment for h2^T = W2^T @ h1^T:
//   lane(c,g) elem j  ->  W2[k = g*8+j][unit = n*16+c]
// Frags 4+kk*2+n2: W3 as B-fragment for t = h2 @ W3, u-map matching GEMM1's D order:
//   lane(c,g) elem j  ->  W3[u = (kk*2+(j>>2))*16 + g*4 + (j&3)][n2*16+c]
__global__ __launch_bounds__(256)
void honam_prep(const float* __restrict__ w2g, const float* __restrict__ w3g,
                unsigned short* __restrict__ wf)
{
    const int f   = blockIdx.x;
    const int tid = threadIdx.x;
    const float* w2 = w2g + (size_t)f * 2048;
    const float* w3 = w3g + (size_t)f * 2048;
    unsigned short* dst = wf + (size_t)f * 4096;
    for (int i = tid; i < 4096; i += 256) {
        const int frag = i >> 9;
        const int l    = (i >> 3) & 63;
        const int j    = i & 7;
        const int c    = l & 15;
        const int g    = l >> 4;
        float v;
        if (frag < 4) {
            v = w2[(g * 8 + j) * 64 + frag * 16 + c];            // W2[k][n*16+c]
        } else {
            const int kk = (frag - 4) >> 1;
            const int n2 = (frag - 4) & 1;
            const int u  = (kk * 2 + (j >> 2)) * 16 + g * 4 + (j & 3);
            v = w3[u * 32 + n2 * 16 + c];                        // W3[u][n2*16+c]
        }
        dst[i] = f2bf(v);
    }
}

// ---------------- Kernel 1: MFMA feature nets + p1/p2 partials (NO atomics) ----------------
__global__ __launch_bounds__(256, 3)
void honam_k1(const float* __restrict__ xg,
              const float* __restrict__ w1g, const float* __restrict__ b1g,
              const float* __restrict__ b2g, const float* __restrict__ b3g,
              const unsigned short* __restrict__ wfg,
              float* __restrict__ p1part, float* __restrict__ p2part)
{
    __shared__ float xs[NF][RPB];     // x-tile transposed: 16 features x 128 rows = 8KB

    const int tid  = threadIdx.x;
    const int wave = tid >> 6;
    const int lane = tid & 63;
    const int c16  = lane & 15;
    const int g4   = lane >> 4;

    const int bx = blockIdx.x;
    const int rb = bx >> 4;           // 0..63
    const int fc = bx & 15;           // 0..15
    const int r0 = rb * RPB;
    const int f0 = fc * NF;

    // ---- stage x-tile once, coalesced, stored transposed ----
    {
        const int row  = tid >> 1;    // 0..127
        const int half = tid & 1;     // 0..1
        const float4 va = *(const float4*)&xg[(size_t)(r0 + row) * F_ + f0 + half * 8];
        const float4 vb = *(const float4*)&xg[(size_t)(r0 + row) * F_ + f0 + half * 8 + 4];
        const int fb = half * 8;
        xs[fb + 0][row] = va.x; xs[fb + 1][row] = va.y;
        xs[fb + 2][row] = va.z; xs[fb + 3][row] = va.w;
        xs[fb + 4][row] = vb.x; xs[fb + 5][row] = vb.y;
        xs[fb + 6][row] = vb.z; xs[fb + 7][row] = vb.w;
    }
    __syncthreads();   // the only barrier in this kernel

    float pacc1[NSUB][2][4];
    float pacc2[NSUB][2][4];
#pragma unroll
    for (int s = 0; s < NSUB; ++s)
#pragma unroll
        for (int n2 = 0; n2 < 2; ++n2)
#pragma unroll
            for (int j = 0; j < 4; ++j) { pacc1[s][n2][j] = 0.f; pacc2[s][n2][j] = 0.f; }

    // per-lane weight-frag base: feature stride 8192 B, lane offset 16 B
    const char* wlane = (const char*)wfg + (size_t)f0 * 8192 + (size_t)lane * 16;

    v8s wcur[8], wnxt[8];
#pragma unroll
    for (int fr = 0; fr < 8; ++fr)
        wcur[fr] = *(const v8s*)(wlane + fr * 1024);

#pragma unroll 2
    for (int fi = 0; fi < NF; ++fi) {
        const int f = f0 + fi;
        // prefetch next feature's frags (one full compute phase of latency hiding)
        if (fi + 1 < NF) {
            const char* wn = wlane + (size_t)(fi + 1) * 8192;
#pragma unroll
            for (int fr = 0; fr < 8; ++fr)
                wnxt[fr] = *(const v8s*)(wn + fr * 1024);
        }
        // hoist LDS x reads for both subtiles
        float xm[NSUB];
#pragma unroll
        for (int s = 0; s < NSUB; ++s)
            xm[s] = xs[fi][s * 64 + wave * 16 + c16];

        // per-feature scalars (f32, L1-cached)
        const float4 w1a = *(const float4*)&w1g[f * 32 + g4 * 8];
        const float4 w1b = *(const float4*)&w1g[f * 32 + g4 * 8 + 4];
        const float4 b1a = *(const float4*)&b1g[f * 32 + g4 * 8];
        const float4 b1b = *(const float4*)&b1g[f * 32 + g4 * 8 + 4];
        const float w1v[8] = {w1a.x, w1a.y, w1a.z, w1a.w, w1b.x, w1b.y, w1b.z, w1b.w};
        const float b1v[8] = {b1a.x, b1a.y, b1a.z, b1a.w, b1b.x, b1b.y, b1b.z, b1b.w};
        // b2 as per-reg C-in for swapped GEMM1: reg j <-> unit n*16+g4*4+j
        float4 b2c[4];
#pragma unroll
        for (int n = 0; n < 4; ++n)
            b2c[n] = *(const float4*)&b2g[f * 64 + n * 16 + g4 * 4];
        float b3v[2];
#pragma unroll
        for (int n = 0; n < 2; ++n) b3v[n] = b3g[f * 32 + n * 16 + c16];

#pragma unroll
        for (int sub = 0; sub < NSUB; ++sub) {
            // h1 as B-frag of GEMM1: lane(c16,g4) elem j = h1[m=c16][k=g4*8+j]
            unsigned h1p[4];
#pragma unroll
            for (int jj = 0; jj < 4; ++jj) {
                const float e0 = fmaxf(fmaf(xm[sub], w1v[2 * jj],     b1v[2 * jj]),     0.f);
                const float e1 = fmaxf(fmaf(xm[sub], w1v[2 * jj + 1], b1v[2 * jj + 1]), 0.f);
                h1p[jj] = cvtpk(e0, e1);
            }
            const v8s bh1 = __builtin_bit_cast(v8s, (v4u){h1p[0], h1p[1], h1p[2], h1p[3]});

            // GEMM1 (swapped): h2^T = W2^T @ h1^T + b2 ; D reg j = h2[m=c16][n*16+g4*4+j]
            v4f acc2[4];
#pragma unroll
            for (int n = 0; n < 4; ++n)
                acc2[n] = __builtin_amdgcn_mfma_f32_16x16x32_bf16(
                    wcur[n], bh1, (v4f){b2c[n].x, b2c[n].y, b2c[n].z, b2c[n].w}, 0, 0, 0);

            // relu + pack: D-frags ARE GEMM2's A-frags under the prep-side u-map
            unsigned q[8];
#pragma unroll
            for (int n = 0; n < 4; ++n) {
                q[2 * n]     = cvtpk(fmaxf(acc2[n][0], 0.f), fmaxf(acc2[n][1], 0.f));
                q[2 * n + 1] = cvtpk(fmaxf(acc2[n][2], 0.f), fmaxf(acc2[n][3], 0.f));
            }
            const v8s a2k0 = __builtin_bit_cast(v8s, (v4u){q[0], q[1], q[2], q[3]});
            const v8s a2k1 = __builtin_bit_cast(v8s, (v4u){q[4], q[5], q[6], q[7]});

            // GEMM2: t = relu(h2 @ W3 + b3)
            v4f acc3[2];
#pragma unroll
            for (int n2 = 0; n2 < 2; ++n2) {
                acc3[n2] = __builtin_amdgcn_mfma_f32_16x16x32_bf16(
                    a2k0, wcur[4 + n2], (v4f){b3v[n2], b3v[n2], b3v[n2], b3v[n2]}, 0, 0, 0);
                acc3[n2] = __builtin_amdgcn_mfma_f32_16x16x32_bf16(
                    a2k1, wcur[6 + n2], acc3[n2], 0, 0, 0);
            }
#pragma unroll
            for (int n2 = 0; n2 < 2; ++n2)
#pragma unroll
                for (int j = 0; j < 4; ++j) {
                    const float t = fmaxf(acc3[n2][j], 0.f);
                    pacc1[sub][n2][j] += t;
                    pacc2[sub][n2][j] = fmaf(t, t, pacc2[sub][n2][j]);
                }
        }
        // rotate prefetch buffer (renamed away under unroll 2)
#pragma unroll
        for (int fr = 0; fr < 8; ++fr) wcur[fr] = wnxt[fr];
    }

    // ---- write disjoint per-chunk partials (no atomics, fire-and-forget) ----
    float* p1c = p1part + (size_t)fc * (B_ * 32);
    float* p2c = p2part + (size_t)fc * (B_ * 32);
#pragma unroll
    for (int sub = 0; sub < NSUB; ++sub)
#pragma unroll
        for (int n2 = 0; n2 < 2; ++n2)
#pragma unroll
            for (int j = 0; j < 4; ++j) {
                const int row = r0 + sub * 64 + wave * 16 + g4 * 4 + j;
                const int col = n2 * 16 + c16;
                p1c[row * 32 + col] = pacc1[sub][n2][j];
                p2c[row * 32 + col] = pacc2[sub][n2][j];
            }
}

// ---------------- Kernel 2: 16-way partial reduce + Newton identities + head ----------------
__global__ __launch_bounds__(256)
void honam_k2(const float* __restrict__ p1part, const float* __restrict__ p2part,
              const float* __restrict__ woutg, const float* __restrict__ boutg,
              float* __restrict__ outg)
{
    const int tid = threadIdx.x;
    const int o   = tid & 31;
    const int r   = blockIdx.x * 8 + (tid >> 5);
    const size_t idx = (size_t)r * 32 + o;

    float s1 = 0.f, s2 = 0.f;
#pragma unroll
    for (int fc = 0; fc < NFC; ++fc) {
        s1 += p1part[(size_t)fc * (B_ * 32) + idx];
        s2 += p2part[(size_t)fc * (B_ * 32) + idx];
    }
    const float wa = woutg[o];
    const float wb = woutg[32 + o];
    float val = s1 * wa + 0.5f * (s1 * s1 - s2) * wb;
#pragma unroll
    for (int off = 16; off > 0; off >>= 1)
        val += __shfl_down(val, off, 32);
    if (o == 0) outg[r] = val + boutg[0];
}

extern "C" void kernel_launch(void* const* d_in, const int* in_sizes, int n_in,
                              void* d_out, int out_size, void* d_ws, size_t ws_size,
                              hipStream_t stream)
{
    const float* xg    = (const float*)d_in[0];
    const float* w1g   = (const float*)d_in[1];
    const float* b1g   = (const float*)d_in[2];
    const float* w2g   = (const float*)d_in[3];
    const float* b2g   = (const float*)d_in[4];
    const float* w3g   = (const float*)d_in[5];
    const float* b3g   = (const float*)d_in[6];
    const float* woutg = (const float*)d_in[7];
    const float* boutg = (const float*)d_in[8];
    float* outg = (float*)d_out;

    // workspace: p1part 16MB | p2part 16MB | packed weights 2MB (all fully
    // overwritten every call -> no memset needed, deterministic)
    float* p1part = (float*)d_ws;
    float* p2part = p1part + (size_t)NFC * B_ * 32;
    unsigned short* wf = (unsigned short*)(p2part + (size_t)NFC * B_ * 32);

    honam_prep<<<dim3(F_), dim3(256), 0, stream>>>(w2g, w3g, wf);

    honam_k1<<<dim3((B_ / RPB) * NFC), dim3(256), 0, stream>>>(
        xg, w1g, b1g, b2g, b3g, wf, p1part, p2part);

    honam_k2<<<dim3(B_ / 8), dim3(256), 0, stream>>>(p1part, p2part, woutg, boutg, outg);
}

// Round 10
// 59.401 us; speedup vs baseline: 2.8388x; 1.0736x over previous
//
#include <hip/hip_runtime.h>
#include <hip/hip_bf16.h>

#define B_   8192
#define F_   256
#define NFC  16            // feature chunks (blocks along F)
#define NF   (F_/NFC)      // 16 features per block
#define RPB  128           // rows per block
#define NSUB 2             // 2 subtiles of 64 rows (4 waves x 16 rows)

typedef __attribute__((ext_vector_type(8))) short v8s;   // bf16x8 A/B frag (4 VGPR)
typedef __attribute__((ext_vector_type(4))) float v4f;   // f32x4 C/D frag
typedef __attribute__((ext_vector_type(4))) unsigned int v4u;

static __device__ __forceinline__ unsigned short f2bf(float f) {
    __hip_bfloat16 h = __float2bfloat16(f);
    return __builtin_bit_cast(unsigned short, h);
}

// single-instruction packed f32->bf16x2 (low=a, high=b), RNE (gfx950)
static __device__ __forceinline__ unsigned cvtpk(float a, float b) {
    unsigned r;
    asm("v_cvt_pk_bf16_f32 %0, %1, %2" : "=v"(r) : "v"(a), "v"(b));
    return r;
}

// ---------------- prep: pack W2/W3 into MFMA fragment order, bf16 ----------------
// Frags 0..3: W2 tile n as A-fragment for h2^T = W2^T @ h1^T:
//   lane(c,g) elem j  ->  W2[k = g*8+j][unit = n*16+c]
// Frags 4+kk*2+n2: W3 as B-fragment for t = h2 @ W3, u-map matching GEMM1's D order:
//   lane(c,g) elem j  ->  W3[u = (kk*2+(j>>2))*16 + g*4 + (j&3)][n2*16+c]
__global__ __launch_bounds__(256)
void honam_prep(const float* __restrict__ w2g, const float* __restrict__ w3g,
                unsigned short* __restrict__ wf)
{
    const int f   = blockIdx.x;
    const int tid = threadIdx.x;
    const float* w2 = w2g + (size_t)f * 2048;
    const float* w3 = w3g + (size_t)f * 2048;
    unsigned short* dst = wf + (size_t)f * 4096;
    for (int i = tid; i < 4096; i += 256) {
        const int frag = i >> 9;
        const int l    = (i >> 3) & 63;
        const int j    = i & 7;
        const int c    = l & 15;
        const int g    = l >> 4;
        float v;
        if (frag < 4) {
            v = w2[(g * 8 + j) * 64 + frag * 16 + c];            // W2[k][n*16+c]
        } else {
            const int kk = (frag - 4) >> 1;
            const int n2 = (frag - 4) & 1;
            const int u  = (kk * 2 + (j >> 2)) * 16 + g * 4 + (j & 3);
            v = w3[u * 32 + n2 * 16 + c];                        // W3[u][n2*16+c]
        }
        dst[i] = f2bf(v);
    }
}

// per-feature register set (all statically indexed -> stays in VGPRs)
struct FeatRegs {
    v8s    w[8];      // 8 MFMA fragments
    float4 w1[2];     // W1[g4*8 .. +7]
    float4 b1[2];
    float4 b2[4];     // b2 C-in slices
    float  b3[2];
};

// ---------------- Kernel 1: MFMA feature nets + p1/p2 partials (no atomics) ----------------
__global__ __launch_bounds__(256, 2)
void honam_k1(const float* __restrict__ xg,
              const float* __restrict__ w1g, const float* __restrict__ b1g,
              const float* __restrict__ b2g, const float* __restrict__ b3g,
              const unsigned short* __restrict__ wfg,
              float* __restrict__ p1part, float* __restrict__ p2part)
{
    __shared__ float xs[NF][RPB];     // x-tile transposed: 16 features x 128 rows = 8KB

    const int tid  = threadIdx.x;
    const int wave = tid >> 6;
    const int lane = tid & 63;
    const int c16  = lane & 15;
    const int g4   = lane >> 4;

    const int bx = blockIdx.x;
    const int rb = bx >> 4;           // 0..63
    const int fc = bx & 15;           // 0..15
    const int r0 = rb * RPB;
    const int f0 = fc * NF;

    // ---- stage x-tile once, coalesced, stored transposed ----
    {
        const int row  = tid >> 1;    // 0..127
        const int half = tid & 1;     // 0..1
        const float4 va = *(const float4*)&xg[(size_t)(r0 + row) * F_ + f0 + half * 8];
        const float4 vb = *(const float4*)&xg[(size_t)(r0 + row) * F_ + f0 + half * 8 + 4];
        const int fb = half * 8;
        xs[fb + 0][row] = va.x; xs[fb + 1][row] = va.y;
        xs[fb + 2][row] = va.z; xs[fb + 3][row] = va.w;
        xs[fb + 4][row] = vb.x; xs[fb + 5][row] = vb.y;
        xs[fb + 6][row] = vb.z; xs[fb + 7][row] = vb.w;
    }
    __syncthreads();   // the only barrier in this kernel

    float pacc1[NSUB][2][4];
    float pacc2[NSUB][2][4];
#pragma unroll
    for (int s = 0; s < NSUB; ++s)
#pragma unroll
        for (int n2 = 0; n2 < 2; ++n2)
#pragma unroll
            for (int j = 0; j < 4; ++j) { pacc1[s][n2][j] = 0.f; pacc2[s][n2][j] = 0.f; }

    // per-lane weight-frag base: feature stride 8192 B, lane offset 16 B
    const char* wlane = (const char*)wfg + (size_t)f0 * 8192 + (size_t)lane * 16;

    FeatRegs A, B;

    // loader: fill a FeatRegs for local feature index fl (issues 18 VMEM loads)
    auto loadFeat = [&](FeatRegs& R, int fl) {
        const int f = f0 + fl;
        const char* wp = wlane + (size_t)fl * 8192;
#pragma unroll
        for (int fr = 0; fr < 8; ++fr)
            R.w[fr] = *(const v8s*)(wp + fr * 1024);
        R.w1[0] = *(const float4*)&w1g[f * 32 + g4 * 8];
        R.w1[1] = *(const float4*)&w1g[f * 32 + g4 * 8 + 4];
        R.b1[0] = *(const float4*)&b1g[f * 32 + g4 * 8];
        R.b1[1] = *(const float4*)&b1g[f * 32 + g4 * 8 + 4];
#pragma unroll
        for (int n = 0; n < 4; ++n)
            R.b2[n] = *(const float4*)&b2g[f * 64 + n * 16 + g4 * 4];
        R.b3[0] = b3g[f * 32 + c16];
        R.b3[1] = b3g[f * 32 + 16 + c16];
    };

    // compute: consume cur regs for local feature fl (NO VMEM loads in here)
    auto compute = [&](const FeatRegs& R, int fl) {
        float xm[NSUB];
#pragma unroll
        for (int s = 0; s < NSUB; ++s)
            xm[s] = xs[fl][s * 64 + wave * 16 + c16];
        const float w1v[8] = {R.w1[0].x, R.w1[0].y, R.w1[0].z, R.w1[0].w,
                              R.w1[1].x, R.w1[1].y, R.w1[1].z, R.w1[1].w};
        const float b1v[8] = {R.b1[0].x, R.b1[0].y, R.b1[0].z, R.b1[0].w,
                              R.b1[1].x, R.b1[1].y, R.b1[1].z, R.b1[1].w};
#pragma unroll
        for (int sub = 0; sub < NSUB; ++sub) {
            // h1 as B-frag of GEMM1: lane(c16,g4) elem j = h1[m=c16][k=g4*8+j]
            unsigned h1p[4];
#pragma unroll
            for (int jj = 0; jj < 4; ++jj) {
                const float e0 = fmaxf(fmaf(xm[sub], w1v[2 * jj],     b1v[2 * jj]),     0.f);
                const float e1 = fmaxf(fmaf(xm[sub], w1v[2 * jj + 1], b1v[2 * jj + 1]), 0.f);
                h1p[jj] = cvtpk(e0, e1);
            }
            const v8s bh1 = __builtin_bit_cast(v8s, (v4u){h1p[0], h1p[1], h1p[2], h1p[3]});

            // GEMM1 (swapped): h2^T = W2^T @ h1^T + b2 ; D reg j = h2[m=c16][n*16+g4*4+j]
            v4f acc2[4];
#pragma unroll
            for (int n = 0; n < 4; ++n)
                acc2[n] = __builtin_amdgcn_mfma_f32_16x16x32_bf16(
                    R.w[n], bh1, (v4f){R.b2[n].x, R.b2[n].y, R.b2[n].z, R.b2[n].w}, 0, 0, 0);

            // relu + pack: D-frags ARE GEMM2's A-frags under the prep-side u-map
            unsigned q[8];
#pragma unroll
            for (int n = 0; n < 4; ++n) {
                q[2 * n]     = cvtpk(fmaxf(acc2[n][0], 0.f), fmaxf(acc2[n][1], 0.f));
                q[2 * n + 1] = cvtpk(fmaxf(acc2[n][2], 0.f), fmaxf(acc2[n][3], 0.f));
            }
            const v8s a2k0 = __builtin_bit_cast(v8s, (v4u){q[0], q[1], q[2], q[3]});
            const v8s a2k1 = __builtin_bit_cast(v8s, (v4u){q[4], q[5], q[6], q[7]});

            // GEMM2: t = relu(h2 @ W3 + b3)
            v4f acc3[2];
#pragma unroll
            for (int n2 = 0; n2 < 2; ++n2) {
                acc3[n2] = __builtin_amdgcn_mfma_f32_16x16x32_bf16(
                    a2k0, R.w[4 + n2], (v4f){R.b3[n2], R.b3[n2], R.b3[n2], R.b3[n2]}, 0, 0, 0);
                acc3[n2] = __builtin_amdgcn_mfma_f32_16x16x32_bf16(
                    a2k1, R.w[6 + n2], acc3[n2], 0, 0, 0);
            }
#pragma unroll
            for (int n2 = 0; n2 < 2; ++n2)
#pragma unroll
                for (int j = 0; j < 4; ++j) {
                    const float t = fmaxf(acc3[n2][j], 0.f);
                    pacc1[sub][n2][j] += t;
                    pacc2[sub][n2][j] = fmaf(t, t, pacc2[sub][n2][j]);
                }
        }
    };

    // ---- software pipeline: loads for f+1 issue before compute of f ----
    loadFeat(A, 0);
    for (int fi = 0; fi < NF; fi += 2) {
        loadFeat(B, (fi + 1 < NF) ? fi + 1 : NF - 1);  // clamp: harmless re-load at tail
        compute(A, fi);
        loadFeat(A, (fi + 2 < NF) ? fi + 2 : NF - 1);
        compute(B, fi + 1);
    }

    // ---- write disjoint per-chunk partials (no atomics, fire-and-forget) ----
    float* p1c = p1part + (size_t)fc * (B_ * 32);
    float* p2c = p2part + (size_t)fc * (B_ * 32);
#pragma unroll
    for (int sub = 0; sub < NSUB; ++sub)
#pragma unroll
        for (int n2 = 0; n2 < 2; ++n2)
#pragma unroll
            for (int j = 0; j < 4; ++j) {
                const int row = r0 + sub * 64 + wave * 16 + g4 * 4 + j;
                const int col = n2 * 16 + c16;
                p1c[row * 32 + col] = pacc1[sub][n2][j];
                p2c[row * 32 + col] = pacc2[sub][n2][j];
            }
}

// ---------------- Kernel 2: 16-way partial reduce + Newton identities + head ----------------
__global__ __launch_bounds__(256)
void honam_k2(const float* __restrict__ p1part, const float* __restrict__ p2part,
              const float* __restrict__ woutg, const float* __restrict__ boutg,
              float* __restrict__ outg)
{
    const int tid = threadIdx.x;
    const int o   = tid & 31;
    const int r   = blockIdx.x * 8 + (tid >> 5);
    const size_t idx = (size_t)r * 32 + o;

    float s1 = 0.f, s2 = 0.f;
#pragma unroll
    for (int fc = 0; fc < NFC; ++fc) {
        s1 += p1part[(size_t)fc * (B_ * 32) + idx];
        s2 += p2part[(size_t)fc * (B_ * 32) + idx];
    }
    const float wa = woutg[o];
    const float wb = woutg[32 + o];
    float val = s1 * wa + 0.5f * (s1 * s1 - s2) * wb;
#pragma unroll
    for (int off = 16; off > 0; off >>= 1)
        val += __shfl_down(val, off, 32);
    if (o == 0) outg[r] = val + boutg[0];
}

extern "C" void kernel_launch(void* const* d_in, const int* in_sizes, int n_in,
                              void* d_out, int out_size, void* d_ws, size_t ws_size,
                              hipStream_t stream)
{
    const float* xg    = (const float*)d_in[0];
    const float* w1g   = (const float*)d_in[1];
    const float* b1g   = (const float*)d_in[2];
    const float* w2g   = (const float*)d_in[3];
    const float* b2g   = (const float*)d_in[4];
    const float* w3g   = (const float*)d_in[5];
    const float* b3g   = (const float*)d_in[6];
    const float* woutg = (const float*)d_in[7];
    const float* boutg = (const float*)d_in[8];
    float* outg = (float*)d_out;

    // workspace: p1part 16MB | p2part 16MB | packed weights 2MB (all fully
    // overwritten every call -> no memset needed, deterministic)
    float* p1part = (float*)d_ws;
    float* p2part = p1part + (size_t)NFC * B_ * 32;
    unsigned short* wf = (unsigned short*)(p2part + (size_t)NFC * B_ * 32);

    honam_prep<<<dim3(F_), dim3(256), 0, stream>>>(w2g, w3g, wf);

    honam_k1<<<dim3((B_ / RPB) * NFC), dim3(256), 0, stream>>>(
        xg, w1g, b1g, b2g, b3g, wf, p1part, p2part);

    honam_k2<<<dim3(B_ / 8), dim3(256), 0, stream>>>(p1part, p2part, woutg, boutg, outg);
}

// Round 11
// 52.992 us; speedup vs baseline: 3.1821x; 1.1209x over previous
//
#include <hip/hip_runtime.h>
#include <hip/hip_bf16.h>

#define B_   8192
#define F_   256
#define NFC  16            // feature chunks (blocks along F)
#define NF   (F_/NFC)      // 16 features per block
#define RPB  128           // rows per block
#define NSUB 2             // 2 subtiles of 64 rows (4 waves x 16 rows)

typedef __attribute__((ext_vector_type(8))) short v8s;   // bf16x8 A/B frag (4 VGPR)
typedef __attribute__((ext_vector_type(4))) float v4f;   // f32x4 C/D frag
typedef __attribute__((ext_vector_type(4))) unsigned int v4u;

static __device__ __forceinline__ unsigned short f2bf(float f) {
    __hip_bfloat16 h = __float2bfloat16(f);
    return __builtin_bit_cast(unsigned short, h);
}

// single-instruction packed f32->bf16x2 (low=a, high=b), RNE (gfx950)
static __device__ __forceinline__ unsigned cvtpk(float a, float b) {
    unsigned r;
    asm("v_cvt_pk_bf16_f32 %0, %1, %2" : "=v"(r) : "v"(a), "v"(b));
    return r;
}

// async global->LDS, 16B per lane: LDS dest = uniform base + lane*16 (HW),
// global src = per-lane address. Tracked by vmcnt; __syncthreads drains it.
static __device__ __forceinline__ void gload_lds16(const void* g, void* l) {
    __builtin_amdgcn_global_load_lds(
        (const __attribute__((address_space(1))) unsigned int*)g,
        (__attribute__((address_space(3))) unsigned int*)l,
        16, 0, 0);
}

// ---------------- prep: pack W2/W3 into MFMA fragment order + params array ----------------
// Frags 0..3: W2 tile n as A-fragment for h2^T = W2^T @ h1^T:
//   lane(c,g) elem j  ->  W2[k = g*8+j][unit = n*16+c]
// Frags 4+kk*2+n2: W3 as B-fragment for t = h2 @ W3, u-map matching GEMM1's D order:
//   lane(c,g) elem j  ->  W3[u = (kk*2+(j>>2))*16 + g*4 + (j&3)][n2*16+c]
// Params pp[f][160] f32: [0..31]=W1, [32..63]=b1, [64..127]=b2, [128..159]=b3
__global__ __launch_bounds__(256)
void honam_prep(const float* __restrict__ w2g, const float* __restrict__ w3g,
                const float* __restrict__ w1g, const float* __restrict__ b1g,
                const float* __restrict__ b2g, const float* __restrict__ b3g,
                unsigned short* __restrict__ wf, float* __restrict__ pp)
{
    const int f   = blockIdx.x;
    const int tid = threadIdx.x;
    const float* w2 = w2g + (size_t)f * 2048;
    const float* w3 = w3g + (size_t)f * 2048;
    unsigned short* dst = wf + (size_t)f * 4096;
    for (int i = tid; i < 4096; i += 256) {
        const int frag = i >> 9;
        const int l    = (i >> 3) & 63;
        const int j    = i & 7;
        const int c    = l & 15;
        const int g    = l >> 4;
        float v;
        if (frag < 4) {
            v = w2[(g * 8 + j) * 64 + frag * 16 + c];            // W2[k][n*16+c]
        } else {
            const int kk = (frag - 4) >> 1;
            const int n2 = (frag - 4) & 1;
            const int u  = (kk * 2 + (j >> 2)) * 16 + g * 4 + (j & 3);
            v = w3[u * 32 + n2 * 16 + c];                        // W3[u][n2*16+c]
        }
        dst[i] = f2bf(v);
    }
    if (tid < 160) {
        float v;
        if (tid < 32)       v = w1g[f * 32 + tid];
        else if (tid < 64)  v = b1g[f * 32 + (tid - 32)];
        else if (tid < 128) v = b2g[f * 64 + (tid - 64)];
        else                v = b3g[f * 32 + (tid - 128)];
        pp[(size_t)f * 160 + tid] = v;
    }
}

// ---------------- Kernel 1: MFMA feature nets, LDS-pipelined weights ----------------
__global__ __launch_bounds__(256, 4)
void honam_k1(const float* __restrict__ xg,
              const unsigned short* __restrict__ wfg, const float* __restrict__ ppg,
              float* __restrict__ p1part, float* __restrict__ p2part)
{
    __shared__ float xs[NF][RPB];                                 // 8 KB x-tile (transposed)
    __shared__ float ps[NF * 160];                                // 10 KB all params of chunk
    __shared__ short wbuf[2][4096] __attribute__((aligned(16)));  // 2 x 8 KB frag double-buffer

    const int tid  = threadIdx.x;
    const int wave = tid >> 6;
    const int lane = tid & 63;
    const int c16  = lane & 15;
    const int g4   = lane >> 4;

    const int bx = blockIdx.x;
    const int rb = bx >> 4;           // 0..63
    const int fc = bx & 15;           // 0..15
    const int r0 = rb * RPB;
    const int f0 = fc * NF;

    // ---- stage x-tile once, coalesced, stored transposed ----
    {
        const int row  = tid >> 1;    // 0..127
        const int half = tid & 1;     // 0..1
        const float4 va = *(const float4*)&xg[(size_t)(r0 + row) * F_ + f0 + half * 8];
        const float4 vb = *(const float4*)&xg[(size_t)(r0 + row) * F_ + f0 + half * 8 + 4];
        const int fb = half * 8;
        xs[fb + 0][row] = va.x; xs[fb + 1][row] = va.y;
        xs[fb + 2][row] = va.z; xs[fb + 3][row] = va.w;
        xs[fb + 4][row] = vb.x; xs[fb + 5][row] = vb.y;
        xs[fb + 6][row] = vb.z; xs[fb + 7][row] = vb.w;
    }
    // ---- stage all params of this chunk once (640 float4) ----
    {
        const float4* src = (const float4*)(ppg + (size_t)f0 * 160);
        float4* dst = (float4*)ps;
        dst[tid]       = src[tid];
        dst[tid + 256] = src[tid + 256];
        if (tid < 128) dst[tid + 512] = src[tid + 512];
    }
    // ---- prologue: async-stage feature 0's frags (wave w stages frags 2w,2w+1) ----
    {
        const char* src = (const char*)wfg + (size_t)f0 * 8192 + (2 * wave) * 1024 + lane * 16;
        gload_lds16(src,        &wbuf[0][(2 * wave) * 512]);
        gload_lds16(src + 1024, &wbuf[0][(2 * wave + 1) * 512]);
    }
    __syncthreads();   // drains gload (vmcnt) + LDS stores

    float pacc1[NSUB][2][4];
    float pacc2[NSUB][2][4];
#pragma unroll
    for (int s = 0; s < NSUB; ++s)
#pragma unroll
        for (int n2 = 0; n2 < 2; ++n2)
#pragma unroll
            for (int j = 0; j < 4; ++j) { pacc1[s][n2][j] = 0.f; pacc2[s][n2][j] = 0.f; }

#pragma unroll 2
    for (int fi = 0; fi < NF; ++fi) {
        const int cur = fi & 1;
        // async-stage next feature's frags into the other buffer (zero VGPR cost)
        if (fi + 1 < NF) {
            const char* src = (const char*)wfg + (size_t)(f0 + fi + 1) * 8192
                            + (2 * wave) * 1024 + lane * 16;
            gload_lds16(src,        &wbuf[cur ^ 1][(2 * wave) * 512]);
            gload_lds16(src + 1024, &wbuf[cur ^ 1][(2 * wave + 1) * 512]);
        }
        // fragments just-in-time from LDS (8 x ds_read_b128)
        v8s wfr[8];
#pragma unroll
        for (int fr = 0; fr < 8; ++fr)
            wfr[fr] = *(const v8s*)&wbuf[cur][fr * 512 + lane * 8];

        // params from LDS (broadcast-friendly reads)
        const float4 w1a = *(const float4*)&ps[fi * 160 + g4 * 8];
        const float4 w1b = *(const float4*)&ps[fi * 160 + g4 * 8 + 4];
        const float4 b1a = *(const float4*)&ps[fi * 160 + 32 + g4 * 8];
        const float4 b1b = *(const float4*)&ps[fi * 160 + 32 + g4 * 8 + 4];
        const float w1v[8] = {w1a.x, w1a.y, w1a.z, w1a.w, w1b.x, w1b.y, w1b.z, w1b.w};
        const float b1v[8] = {b1a.x, b1a.y, b1a.z, b1a.w, b1b.x, b1b.y, b1b.z, b1b.w};
        float4 b2c[4];
#pragma unroll
        for (int n = 0; n < 4; ++n)
            b2c[n] = *(const float4*)&ps[fi * 160 + 64 + n * 16 + g4 * 4];
        float b3v[2];
#pragma unroll
        for (int n = 0; n < 2; ++n) b3v[n] = ps[fi * 160 + 128 + n * 16 + c16];

        float xm[NSUB];
#pragma unroll
        for (int s = 0; s < NSUB; ++s)
            xm[s] = xs[fi][s * 64 + wave * 16 + c16];

#pragma unroll
        for (int sub = 0; sub < NSUB; ++sub) {
            // h1 as B-frag of GEMM1: lane(c16,g4) elem j = h1[m=c16][k=g4*8+j]
            unsigned h1p[4];
#pragma unroll
            for (int jj = 0; jj < 4; ++jj) {
                const float e0 = fmaxf(fmaf(xm[sub], w1v[2 * jj],     b1v[2 * jj]),     0.f);
                const float e1 = fmaxf(fmaf(xm[sub], w1v[2 * jj + 1], b1v[2 * jj + 1]), 0.f);
                h1p[jj] = cvtpk(e0, e1);
            }
            const v8s bh1 = __builtin_bit_cast(v8s, (v4u){h1p[0], h1p[1], h1p[2], h1p[3]});

            // GEMM1 (swapped): h2^T = W2^T @ h1^T + b2 ; D reg j = h2[m=c16][n*16+g4*4+j]
            v4f acc2[4];
#pragma unroll
            for (int n = 0; n < 4; ++n)
                acc2[n] = __builtin_amdgcn_mfma_f32_16x16x32_bf16(
                    wfr[n], bh1, (v4f){b2c[n].x, b2c[n].y, b2c[n].z, b2c[n].w}, 0, 0, 0);

            // relu + pack: D-frags ARE GEMM2's A-frags under the prep-side u-map
            unsigned q[8];
#pragma unroll
            for (int n = 0; n < 4; ++n) {
                q[2 * n]     = cvtpk(fmaxf(acc2[n][0], 0.f), fmaxf(acc2[n][1], 0.f));
                q[2 * n + 1] = cvtpk(fmaxf(acc2[n][2], 0.f), fmaxf(acc2[n][3], 0.f));
            }
            const v8s a2k0 = __builtin_bit_cast(v8s, (v4u){q[0], q[1], q[2], q[3]});
            const v8s a2k1 = __builtin_bit_cast(v8s, (v4u){q[4], q[5], q[6], q[7]});

            // GEMM2: t = relu(h2 @ W3 + b3)
            v4f acc3[2];
#pragma unroll
            for (int n2 = 0; n2 < 2; ++n2) {
                acc3[n2] = __builtin_amdgcn_mfma_f32_16x16x32_bf16(
                    a2k0, wfr[4 + n2], (v4f){b3v[n2], b3v[n2], b3v[n2], b3v[n2]}, 0, 0, 0);
                acc3[n2] = __builtin_amdgcn_mfma_f32_16x16x32_bf16(
                    a2k1, wfr[6 + n2], acc3[n2], 0, 0, 0);
            }
#pragma unroll
            for (int n2 = 0; n2 < 2; ++n2)
#pragma unroll
                for (int j = 0; j < 4; ++j) {
                    const float t = fmaxf(acc3[n2][j], 0.f);
                    pacc1[sub][n2][j] += t;
                    pacc2[sub][n2][j] = fmaf(t, t, pacc2[sub][n2][j]);
                }
        }
        // one barrier per feature: compute done (wbuf[cur] free) + stage into
        // wbuf[cur^1] drained (implicit vmcnt(0) before s_barrier)
        __syncthreads();
    }

    // ---- write disjoint per-chunk partials (no atomics, fire-and-forget) ----
    float* p1c = p1part + (size_t)fc * (B_ * 32);
    float* p2c = p2part + (size_t)fc * (B_ * 32);
#pragma unroll
    for (int sub = 0; sub < NSUB; ++sub)
#pragma unroll
        for (int n2 = 0; n2 < 2; ++n2)
#pragma unroll
            for (int j = 0; j < 4; ++j) {
                const int row = r0 + sub * 64 + wave * 16 + g4 * 4 + j;
                const int col = n2 * 16 + c16;
                p1c[row * 32 + col] = pacc1[sub][n2][j];
                p2c[row * 32 + col] = pacc2[sub][n2][j];
            }
}

// ---------------- Kernel 2: 16-way partial reduce + Newton identities + head ----------------
__global__ __launch_bounds__(256)
void honam_k2(const float* __restrict__ p1part, const float* __restrict__ p2part,
              const float* __restrict__ woutg, const float* __restrict__ boutg,
              float* __restrict__ outg)
{
    const int tid = threadIdx.x;
    const int o   = tid & 31;
    const int r   = blockIdx.x * 8 + (tid >> 5);
    const size_t idx = (size_t)r * 32 + o;

    float s1 = 0.f, s2 = 0.f;
#pragma unroll
    for (int fc = 0; fc < NFC; ++fc) {
        s1 += p1part[(size_t)fc * (B_ * 32) + idx];
        s2 += p2part[(size_t)fc * (B_ * 32) + idx];
    }
    const float wa = woutg[o];
    const float wb = woutg[32 + o];
    float val = s1 * wa + 0.5f * (s1 * s1 - s2) * wb;
#pragma unroll
    for (int off = 16; off > 0; off >>= 1)
        val += __shfl_down(val, off, 32);
    if (o == 0) outg[r] = val + boutg[0];
}

extern "C" void kernel_launch(void* const* d_in, const int* in_sizes, int n_in,
                              void* d_out, int out_size, void* d_ws, size_t ws_size,
                              hipStream_t stream)
{
    const float* xg    = (const float*)d_in[0];
    const float* w1g   = (const float*)d_in[1];
    const float* b1g   = (const float*)d_in[2];
    const float* w2g   = (const float*)d_in[3];
    const float* b2g   = (const float*)d_in[4];
    const float* w3g   = (const float*)d_in[5];
    const float* b3g   = (const float*)d_in[6];
    const float* woutg = (const float*)d_in[7];
    const float* boutg = (const float*)d_in[8];
    float* outg = (float*)d_out;

    // workspace: p1part 16MB | p2part 16MB | frags 2MB | params 160KB
    // (all fully overwritten every call -> no memset needed, deterministic)
    float* p1part = (float*)d_ws;
    float* p2part = p1part + (size_t)NFC * B_ * 32;
    unsigned short* wf = (unsigned short*)(p2part + (size_t)NFC * B_ * 32);
    float* pp = (float*)(wf + (size_t)F_ * 4096);

    honam_prep<<<dim3(F_), dim3(256), 0, stream>>>(w2g, w3g, w1g, b1g, b2g, b3g, wf, pp);

    honam_k1<<<dim3((B_ / RPB) * NFC), dim3(256), 0, stream>>>(
        xg, wf, pp, p1part, p2part);

    honam_k2<<<dim3(B_ / 8), dim3(256), 0, stream>>>(p1part, p2part, woutg, boutg, outg);
}

// Round 12
// 50.134 us; speedup vs baseline: 3.3636x; 1.0570x over previous
//
#include <hip/hip_runtime.h>
#include <hip/hip_bf16.h>

#define B_   8192
#define F_   256
#define NFC  16            // feature chunks (blocks along F)
#define NF   (F_/NFC)      // 16 features per block
#define NPH  (NF/2)        // 8 phases, 2 features each
#define RPB  128           // rows per block
#define NSUB 2             // 2 subtiles of 64 rows (4 waves x 16 rows)

typedef __attribute__((ext_vector_type(8))) short v8s;   // bf16x8 A/B frag (4 VGPR)
typedef __attribute__((ext_vector_type(4))) float v4f;   // f32x4 C/D frag
typedef __attribute__((ext_vector_type(4))) unsigned int v4u;

static __device__ __forceinline__ unsigned short f2bf(float f) {
    __hip_bfloat16 h = __float2bfloat16(f);
    return __builtin_bit_cast(unsigned short, h);
}

// single-instruction packed f32->bf16x2 (low=a, high=b), RNE (gfx950)
static __device__ __forceinline__ unsigned cvtpk(float a, float b) {
    unsigned r;
    asm("v_cvt_pk_bf16_f32 %0, %1, %2" : "=v"(r) : "v"(a), "v"(b));
    return r;
}

// async global->LDS, 16B per lane: LDS dest = uniform base + lane*16 (HW),
// global src = per-lane address. Tracked by vmcnt; __syncthreads drains it.
static __device__ __forceinline__ void gload_lds16(const void* g, void* l) {
    __builtin_amdgcn_global_load_lds(
        (const __attribute__((address_space(1))) unsigned int*)g,
        (__attribute__((address_space(3))) unsigned int*)l,
        16, 0, 0);
}

// ---------------- prep: pack W2/W3 into MFMA fragment order + params array ----------------
// Frags 0..3: W2 tile n as A-fragment for h2^T = W2^T @ h1^T:
//   lane(c,g) elem j  ->  W2[k = g*8+j][unit = n*16+c]
// Frags 4+kk*2+n2: W3 as B-fragment for t = h2 @ W3, u-map matching GEMM1's D order:
//   lane(c,g) elem j  ->  W3[u = (kk*2+(j>>2))*16 + g*4 + (j&3)][n2*16+c]
// Params pp[f][160] f32: [0..31]=W1, [32..63]=b1, [64..127]=b2, [128..159]=b3
__global__ __launch_bounds__(256)
void honam_prep(const float* __restrict__ w2g, const float* __restrict__ w3g,
                const float* __restrict__ w1g, const float* __restrict__ b1g,
                const float* __restrict__ b2g, const float* __restrict__ b3g,
                unsigned short* __restrict__ wf, float* __restrict__ pp)
{
    const int f   = blockIdx.x;
    const int tid = threadIdx.x;
    const float* w2 = w2g + (size_t)f * 2048;
    const float* w3 = w3g + (size_t)f * 2048;
    unsigned short* dst = wf + (size_t)f * 4096;
    for (int i = tid; i < 4096; i += 256) {
        const int frag = i >> 9;
        const int l    = (i >> 3) & 63;
        const int j    = i & 7;
        const int c    = l & 15;
        const int g    = l >> 4;
        float v;
        if (frag < 4) {
            v = w2[(g * 8 + j) * 64 + frag * 16 + c];            // W2[k][n*16+c]
        } else {
            const int kk = (frag - 4) >> 1;
            const int n2 = (frag - 4) & 1;
            const int u  = (kk * 2 + (j >> 2)) * 16 + g * 4 + (j & 3);
            v = w3[u * 32 + n2 * 16 + c];                        // W3[u][n2*16+c]
        }
        dst[i] = f2bf(v);
    }
    if (tid < 160) {
        float v;
        if (tid < 32)       v = w1g[f * 32 + tid];
        else if (tid < 64)  v = b1g[f * 32 + (tid - 32)];
        else if (tid < 128) v = b2g[f * 64 + (tid - 64)];
        else                v = b3g[f * 32 + (tid - 128)];
        pp[(size_t)f * 160 + tid] = v;
    }
}

// ---------------- Kernel 1: MFMA feature nets, 2-feature LDS pipeline ----------------
__global__ __launch_bounds__(256, 3)
void honam_k1(const float* __restrict__ xg,
              const unsigned short* __restrict__ wfg, const float* __restrict__ ppg,
              float* __restrict__ p1part, float* __restrict__ p2part)
{
    __shared__ float xs[NF][RPB];                                    // 8 KB x-tile (transposed)
    __shared__ float ps[NF * 160];                                   // 10 KB all params of chunk
    __shared__ short wbuf[2][2][4096] __attribute__((aligned(16)));  // [set][feat] 2x2x8KB = 32KB

    const int tid  = threadIdx.x;
    const int wave = tid >> 6;
    const int lane = tid & 63;
    const int c16  = lane & 15;
    const int g4   = lane >> 4;

    const int bx = blockIdx.x;
    const int rb = bx >> 4;           // 0..63
    const int fc = bx & 15;           // 0..15
    const int r0 = rb * RPB;
    const int f0 = fc * NF;

    // ---- stage x-tile once, coalesced, stored transposed ----
    {
        const int row  = tid >> 1;    // 0..127
        const int half = tid & 1;     // 0..1
        const float4 va = *(const float4*)&xg[(size_t)(r0 + row) * F_ + f0 + half * 8];
        const float4 vb = *(const float4*)&xg[(size_t)(r0 + row) * F_ + f0 + half * 8 + 4];
        const int fb = half * 8;
        xs[fb + 0][row] = va.x; xs[fb + 1][row] = va.y;
        xs[fb + 2][row] = va.z; xs[fb + 3][row] = va.w;
        xs[fb + 4][row] = vb.x; xs[fb + 5][row] = vb.y;
        xs[fb + 6][row] = vb.z; xs[fb + 7][row] = vb.w;
    }
    // ---- stage all params of this chunk once (640 float4) ----
    {
        const float4* src = (const float4*)(ppg + (size_t)f0 * 160);
        float4* dst = (float4*)ps;
        dst[tid]       = src[tid];
        dst[tid + 256] = src[tid + 256];
        if (tid < 128) dst[tid + 512] = src[tid + 512];
    }

    // stage helper: wave w stages frags 2w,2w+1 of local feature fl into wbuf[set][fp]
    auto stage = [&](int set, int fp, int fl) {
        const char* src = (const char*)wfg + (size_t)(f0 + fl) * 8192
                        + (2 * wave) * 1024 + lane * 16;
        gload_lds16(src,        &wbuf[set][fp][(2 * wave) * 512]);
        gload_lds16(src + 1024, &wbuf[set][fp][(2 * wave + 1) * 512]);
    };

    // ---- prologue: stage features 0,1 into set 0 ----
    stage(0, 0, 0);
    stage(0, 1, 1);
    __syncthreads();   // drains gload (vmcnt) + LDS stores

    float2 pacc1[NSUB][2][2];   // [sub][n2][jpair]
    float2 pacc2[NSUB][2][2];
#pragma unroll
    for (int s = 0; s < NSUB; ++s)
#pragma unroll
        for (int n2 = 0; n2 < 2; ++n2)
#pragma unroll
            for (int jp = 0; jp < 2; ++jp) {
                pacc1[s][n2][jp] = make_float2(0.f, 0.f);
                pacc2[s][n2][jp] = make_float2(0.f, 0.f);
            }

    // compute one feature entirely from LDS (no global loads)
    auto computeFeat = [&](int set, int fp, int fl) {
        const short* wb = &wbuf[set][fp][0];
        v8s wfr[8];
#pragma unroll
        for (int fr = 0; fr < 8; ++fr)
            wfr[fr] = *(const v8s*)&wb[fr * 512 + lane * 8];

        const int fb = fl * 160;
        const float4 w1a = *(const float4*)&ps[fb + g4 * 8];
        const float4 w1b = *(const float4*)&ps[fb + g4 * 8 + 4];
        const float4 b1a = *(const float4*)&ps[fb + 32 + g4 * 8];
        const float4 b1b = *(const float4*)&ps[fb + 32 + g4 * 8 + 4];
        const float w1v[8] = {w1a.x, w1a.y, w1a.z, w1a.w, w1b.x, w1b.y, w1b.z, w1b.w};
        const float b1v[8] = {b1a.x, b1a.y, b1a.z, b1a.w, b1b.x, b1b.y, b1b.z, b1b.w};
        float b3v[2];
#pragma unroll
        for (int n = 0; n < 2; ++n) b3v[n] = ps[fb + 128 + n * 16 + c16];

        float xm[NSUB];
#pragma unroll
        for (int s = 0; s < NSUB; ++s)
            xm[s] = xs[fl][s * 64 + wave * 16 + c16];

#pragma unroll
        for (int sub = 0; sub < NSUB; ++sub) {
            // h1 as B-frag of GEMM1: lane(c16,g4) elem j = h1[m=c16][k=g4*8+j]
            unsigned h1p[4];
#pragma unroll
            for (int jj = 0; jj < 4; ++jj) {
                const float e0 = fmaxf(fmaf(xm[sub], w1v[2 * jj],     b1v[2 * jj]),     0.f);
                const float e1 = fmaxf(fmaf(xm[sub], w1v[2 * jj + 1], b1v[2 * jj + 1]), 0.f);
                h1p[jj] = cvtpk(e0, e1);
            }
            const v8s bh1 = __builtin_bit_cast(v8s, (v4u){h1p[0], h1p[1], h1p[2], h1p[3]});

            // GEMM1 (swapped): h2^T = W2^T @ h1^T + b2 ; b2 C-in straight from LDS
            v4f acc2[4];
#pragma unroll
            for (int n = 0; n < 4; ++n) {
                const v4f b2cv = *(const v4f*)&ps[fb + 64 + n * 16 + g4 * 4];
                acc2[n] = __builtin_amdgcn_mfma_f32_16x16x32_bf16(wfr[n], bh1, b2cv, 0, 0, 0);
            }

            // relu + pack: D-frags ARE GEMM2's A-frags under the prep-side u-map
            unsigned q[8];
#pragma unroll
            for (int n = 0; n < 4; ++n) {
                q[2 * n]     = cvtpk(fmaxf(acc2[n][0], 0.f), fmaxf(acc2[n][1], 0.f));
                q[2 * n + 1] = cvtpk(fmaxf(acc2[n][2], 0.f), fmaxf(acc2[n][3], 0.f));
            }
            const v8s a2k0 = __builtin_bit_cast(v8s, (v4u){q[0], q[1], q[2], q[3]});
            const v8s a2k1 = __builtin_bit_cast(v8s, (v4u){q[4], q[5], q[6], q[7]});

            // GEMM2: t = relu(h2 @ W3 + b3)
            v4f acc3[2];
#pragma unroll
            for (int n2 = 0; n2 < 2; ++n2) {
                acc3[n2] = __builtin_amdgcn_mfma_f32_16x16x32_bf16(
                    a2k0, wfr[4 + n2], (v4f){b3v[n2], b3v[n2], b3v[n2], b3v[n2]}, 0, 0, 0);
                acc3[n2] = __builtin_amdgcn_mfma_f32_16x16x32_bf16(
                    a2k1, wfr[6 + n2], acc3[n2], 0, 0, 0);
            }
            // packed accumulate (v_pk_add / v_pk_fma)
#pragma unroll
            for (int n2 = 0; n2 < 2; ++n2)
#pragma unroll
                for (int jp = 0; jp < 2; ++jp) {
                    float2 t;
                    t.x = fmaxf(acc3[n2][2 * jp],     0.f);
                    t.y = fmaxf(acc3[n2][2 * jp + 1], 0.f);
                    pacc1[sub][n2][jp].x += t.x;
                    pacc1[sub][n2][jp].y += t.y;
                    pacc2[sub][n2][jp].x += t.x * t.x;
                    pacc2[sub][n2][jp].y += t.y * t.y;
                }
        }
    };

    // ---- 8 phases x 2 features; stage next pair before computing current ----
#pragma unroll 2
    for (int ph = 0; ph < NPH; ++ph) {
        const int set = ph & 1;
        if (ph + 1 < NPH) {
            stage(set ^ 1, 0, 2 * ph + 2);
            stage(set ^ 1, 1, 2 * ph + 3);
        }
        computeFeat(set, 0, 2 * ph);
        computeFeat(set, 1, 2 * ph + 1);
        // barrier: compute done (set free) + next pair's gloads drained (vmcnt(0))
        __syncthreads();
    }

    // ---- write disjoint per-chunk partials (no atomics, fire-and-forget) ----
    float* p1c = p1part + (size_t)fc * (B_ * 32);
    float* p2c = p2part + (size_t)fc * (B_ * 32);
#pragma unroll
    for (int sub = 0; sub < NSUB; ++sub)
#pragma unroll
        for (int n2 = 0; n2 < 2; ++n2)
#pragma unroll
            for (int jp = 0; jp < 2; ++jp) {
                const int row = r0 + sub * 64 + wave * 16 + g4 * 4 + 2 * jp;
                const int col = n2 * 16 + c16;
                p1c[row * 32 + col]       = pacc1[sub][n2][jp].x;
                p1c[(row + 1) * 32 + col] = pacc1[sub][n2][jp].y;
                p2c[row * 32 + col]       = pacc2[sub][n2][jp].x;
                p2c[(row + 1) * 32 + col] = pacc2[sub][n2][jp].y;
            }
}

// ---------------- Kernel 2: 16-way partial reduce + Newton identities + head ----------------
__global__ __launch_bounds__(256)
void honam_k2(const float* __restrict__ p1part, const float* __restrict__ p2part,
              const float* __restrict__ woutg, const float* __restrict__ boutg,
              float* __restrict__ outg)
{
    const int tid = threadIdx.x;
    const int o   = tid & 31;
    const int r   = blockIdx.x * 8 + (tid >> 5);
    const size_t idx = (size_t)r * 32 + o;

    float s1 = 0.f, s2 = 0.f;
#pragma unroll
    for (int fc = 0; fc < NFC; ++fc) {
        s1 += p1part[(size_t)fc * (B_ * 32) + idx];
        s2 += p2part[(size_t)fc * (B_ * 32) + idx];
    }
    const float wa = woutg[o];
    const float wb = woutg[32 + o];
    float val = s1 * wa + 0.5f * (s1 * s1 - s2) * wb;
#pragma unroll
    for (int off = 16; off > 0; off >>= 1)
        val += __shfl_down(val, off, 32);
    if (o == 0) outg[r] = val + boutg[0];
}

extern "C" void kernel_launch(void* const* d_in, const int* in_sizes, int n_in,
                              void* d_out, int out_size, void* d_ws, size_t ws_size,
                              hipStream_t stream)
{
    const float* xg    = (const float*)d_in[0];
    const float* w1g   = (const float*)d_in[1];
    const float* b1g   = (const float*)d_in[2];
    const float* w2g   = (const float*)d_in[3];
    const float* b2g   = (const float*)d_in[4];
    const float* w3g   = (const float*)d_in[5];
    const float* b3g   = (const float*)d_in[6];
    const float* woutg = (const float*)d_in[7];
    const float* boutg = (const float*)d_in[8];
    float* outg = (float*)d_out;

    // workspace: p1part 16MB | p2part 16MB | frags 2MB | params 160KB
    // (all fully overwritten every call -> no memset needed, deterministic)
    float* p1part = (float*)d_ws;
    float* p2part = p1part + (size_t)NFC * B_ * 32;
    unsigned short* wf = (unsigned short*)(p2part + (size_t)NFC * B_ * 32);
    float* pp = (float*)(wf + (size_t)F_ * 4096);

    honam_prep<<<dim3(F_), dim3(256), 0, stream>>>(w2g, w3g, w1g, b1g, b2g, b3g, wf, pp);

    honam_k1<<<dim3((B_ / RPB) * NFC), dim3(256), 0, stream>>>(
        xg, wf, pp, p1part, p2part);

    honam_k2<<<dim3(B_ / 8), dim3(256), 0, stream>>>(p1part, p2part, woutg, boutg, outg);
}